// Round 13
// baseline (189.563 us; speedup 1.0000x reference)
//
#include <hip/hip_runtime.h>
#include <math.h>

#define NRES 512
#define CSD  384
#define CZD  128

// workspace layout (float offsets)
#define OFF_Q     0         //  512*192
#define OFF_KT    98304     //  192*512   kkP[h][k][16]
#define OFF_VC    196608    //  512*512   vcomb[k][u]
#define OFF_QP    458752    //  512*144   q_pts row-major
#define OFF_KPT   532480    //  144*512   kptsP[h][k][12]
#define OFF_A     606208    //  3145728: logitsT[h][q][k] (k_bias4->k_sm->k_pair7/k_av2), then part
#define OFF_OCAT  3751936   //  512*2112
#define OFF_WCAT  4833280   //  384*1152 wcat + 1152 bcat
#define OFF_BCAT  (OFF_WCAT + 442368)
#define OFF_PRAWQ 5276800   //  512*144 (k_proj2 -> k_rot)
#define OFF_PRAWK 5350528   //  512*432
#define OFF_WBT   5571712   //  12*128 transposed w_b
#define OFF_PART  OFF_A     //  6*196608 (k_out2 -> k_red)

// ---------------------------------------------------------------- weight concat (+ wbT transpose)
__global__ __launch_bounds__(256) void k_wcat(
    const float* __restrict__ w_q, const float* __restrict__ b_q,
    const float* __restrict__ w_kv, const float* __restrict__ b_kv,
    const float* __restrict__ w_qp, const float* __restrict__ b_qp,
    const float* __restrict__ w_kvp, const float* __restrict__ b_kvp,
    const float* __restrict__ w_b,
    float* __restrict__ wcat, float* __restrict__ bcat, float* __restrict__ wbT)
{
    const int idx = blockIdx.x * 256 + threadIdx.x;
    if (idx < 442368) {
        const int k = idx / 1152, c = idx % 1152;
        float v;
        if (c < 192)      v = w_q[k*192 + c];
        else if (c < 576) v = w_kv[k*384 + (c - 192)];
        else if (c < 720) v = w_qp[k*144 + (c - 576)];
        else              v = w_kvp[k*432 + (c - 720)];
        wcat[idx] = v;
    } else if (idx < 443520) {
        const int c = idx - 442368;
        float v;
        if (c < 192)      v = b_q[c];
        else if (c < 576) v = b_kv[c - 192];
        else if (c < 720) v = b_qp[c - 576];
        else              v = b_kvp[c - 720];
        bcat[c] = v;
    } else if (idx < 445056) {
        const int j = idx - 443520;
        const int h = j >> 7, c = j & 127;
        wbT[h*128 + c] = w_b[c*12 + h];
    }
}

// ---------------------------------------------------------------- projections GEMM
__global__ __launch_bounds__(256) void k_proj2(
    const float* __restrict__ s, const float* __restrict__ wcat, const float* __restrict__ bcat,
    float* __restrict__ q, float* __restrict__ kkP, float* __restrict__ vcomb,
    float* __restrict__ praw_q, float* __restrict__ praw_kv)
{
    const int ct = blockIdx.x;
    const int n0 = blockIdx.y * 32;
    const int t = threadIdx.x;

    __shared__ float sT[32][34];
    __shared__ float wt[32][36];

    const int lr = t >> 3, lc4 = t & 7;
    const int tr = t >> 4, tc = t & 15;
    float4 sv4, wv4;

    sv4 = *(const float4*)&s[(n0 + lr) * CSD + lc4 * 4];
    wv4 = *(const float4*)&wcat[lr * 1152 + ct * 32 + lc4 * 4];
    sT[lc4*4+0][lr] = sv4.x; sT[lc4*4+1][lr] = sv4.y; sT[lc4*4+2][lr] = sv4.z; sT[lc4*4+3][lr] = sv4.w;
    *(float4*)&wt[lr][lc4*4] = wv4;
    __syncthreads();

    float a00 = 0.f, a01 = 0.f, a10 = 0.f, a11 = 0.f;

    for (int it = 0; it < 12; ++it) {
        if (it < 11) {
            const int k0 = (it + 1) * 32;
            sv4 = *(const float4*)&s[(n0 + lr) * CSD + k0 + lc4 * 4];
            wv4 = *(const float4*)&wcat[(k0 + lr) * 1152 + ct * 32 + lc4 * 4];
        }
        #pragma unroll
        for (int kx = 0; kx < 32; ++kx) {
            float2 ss = *(const float2*)&sT[kx][tr * 2];
            float2 ww = *(const float2*)&wt[kx][tc * 2];
            a00 += ss.x * ww.x; a01 += ss.x * ww.y;
            a10 += ss.y * ww.x; a11 += ss.y * ww.y;
        }
        __syncthreads();
        if (it < 11) {
            sT[lc4*4+0][lr] = sv4.x; sT[lc4*4+1][lr] = sv4.y; sT[lc4*4+2][lr] = sv4.z; sT[lc4*4+3][lr] = sv4.w;
            *(float4*)&wt[lr][lc4*4] = wv4;
            __syncthreads();
        }
    }

    float accv[2][2] = {{a00, a01}, {a10, a11}};
    #pragma unroll
    for (int i = 0; i < 2; ++i) {
        const int n = n0 + tr * 2 + i;
        #pragma unroll
        for (int j = 0; j < 2; ++j) {
            const int gcol = ct * 32 + tc * 2 + j;
            const float v = accv[i][j] + bcat[gcol];
            if (gcol < 192) {
                q[n*192 + gcol] = v;
            } else if (gcol < 576) {
                int g = gcol - 192, h = g >> 5, cc = g & 31;
                if (cc < 16) kkP[(size_t)(h*NRES + n)*16 + cc] = v;    // k-major packed
                else         vcomb[n*NRES + h*16 + (cc-16)] = v;
            } else if (gcol < 720) {
                praw_q[n*144 + (gcol - 576)] = v;
            } else {
                praw_kv[n*432 + (gcol - 720)] = v;
            }
        }
    }
}

// ---------------------------------------------------------------- rigid-frame rotation
__global__ __launch_bounds__(256) void k_rot(
    const float* __restrict__ praw_q, const float* __restrict__ praw_kv,
    const float* __restrict__ rot, const float* __restrict__ trans,
    float* __restrict__ q_pts, float* __restrict__ kptsP, float* __restrict__ vcomb)
{
    const int idx = blockIdx.x * 256 + threadIdx.x;
    const int n = idx / 192, u = idx % 192;
    const float* R = rot + n*9;
    const float* T = trans + n*3;
    float px, py, pz;
    if (u < 48) {
        px = praw_q[n*144 + u]; py = praw_q[n*144 + 48 + u]; pz = praw_q[n*144 + 96 + u];
    } else {
        int pt = u - 48;
        px = praw_kv[n*432 + pt]; py = praw_kv[n*432 + 144 + pt]; pz = praw_kv[n*432 + 288 + pt];
    }
    float x  = R[0]*px + R[1]*py + R[2]*pz + T[0];
    float y  = R[3]*px + R[4]*py + R[5]*pz + T[1];
    float zc = R[6]*px + R[7]*py + R[8]*pz + T[2];
    if (u < 48) {
        int o = (n*48 + u)*3;
        q_pts[o] = x; q_pts[o+1] = y; q_pts[o+2] = zc;
    } else {
        int pt = u - 48;
        int h = pt / 12, pp = pt % 12;
        if (pp < 4) {
            size_t o = (size_t)(h*NRES + n)*12 + pp*3;    // k-major packed
            kptsP[o+0] = x; kptsP[o+1] = y; kptsP[o+2] = zc;
        } else {
            int u2 = (h*8 + (pp-4))*3;
            vcomb[n*NRES + 192 + u2+0] = x;
            vcomb[n*NRES + 192 + u2+1] = y;
            vcomb[n*NRES + 192 + u2+2] = zc;
        }
    }
}

// ---------------------------------------------------------------- z pass 1: bias + full logits
// grid (8 k-chunks, 512 q). Swizzled z tile (slot ^= row&7); wb from GLOBAL (broadcast);
// logits read k-major packed kkP/kptsP as float4 (7 vec-loads/head vs 28 b32).
__global__ __launch_bounds__(256) void k_bias4(
    const float* __restrict__ z, const float* __restrict__ wbT, const float* __restrict__ b_b,
    const float* __restrict__ q, const float* __restrict__ kkP,
    const float* __restrict__ q_pts, const float* __restrict__ kptsP,
    const float* __restrict__ head_weights, const float* __restrict__ mask,
    float* __restrict__ logitsT)
{
    const int k0 = blockIdx.x * 64;
    const int qn = blockIdx.y;
    const int t = threadIdx.x;
    __shared__ float zt[64*128];         // float4-slot sc4 = c4 ^ (row&7)
    __shared__ float part[4][64][13];
    __shared__ float q_lds[192];
    __shared__ float qp_lds[144];
    __shared__ float hw_lds[12];

    // stage z tile (coalesced loads, swizzled stores)
    const float4* zp4 = (const float4*)(z + ((size_t)qn*NRES + k0)*CZD);
    float4 zstg[8];
    #pragma unroll
    for (int r = 0; r < 8; ++r) zstg[r] = zp4[t + r*256];
    #pragma unroll
    for (int r = 0; r < 8; ++r) {
        const int idx = t + r*256;
        const int row = idx >> 5, c4 = idx & 31;
        const int sc4 = c4 ^ (row & 7);
        *(float4*)&zt[row*128 + sc4*4] = zstg[r];
    }
    if (t < 192) q_lds[t] = q[qn*192 + t];
    if (t < 144) qp_lds[t] = q_pts[qn*144 + t];
    if (t < 12)  hw_lds[t] = logf(1.f + expf(head_weights[t])) * 0.13608276f;
    __syncthreads();

    // bias compute: kgrp = t&15 (k = kgrp+16*kk), cgrp = (t>>4)&3, hgrp = t>>6
    {
        const int kgrp = t & 15, cgrp = (t >> 4) & 3, hgrp = t >> 6;
        const int h0 = hgrp * 3;
        const int kx7 = kgrp & 7;
        const float* w0 = wbT + (h0+0)*128 + cgrp*32;
        const float* w1 = wbT + (h0+1)*128 + cgrp*32;
        const float* w2 = wbT + (h0+2)*128 + cgrp*32;
        float acc[4][3];
        #pragma unroll
        for (int kk = 0; kk < 4; ++kk)
            #pragma unroll
            for (int j = 0; j < 3; ++j) acc[kk][j] = 0.f;
        #pragma unroll
        for (int j = 0; j < 8; ++j) {
            const int c4 = cgrp*8 + j;
            const float4 wa  = *(const float4*)&w0[j*4];
            const float4 wbv = *(const float4*)&w1[j*4];
            const float4 wc  = *(const float4*)&w2[j*4];
            const int sc4 = c4 ^ kx7;
            #pragma unroll
            for (int kk = 0; kk < 4; ++kk) {
                const int k = kgrp + 16*kk;
                float4 zv = *(const float4*)&zt[k*128 + sc4*4];
                acc[kk][0] += zv.x*wa.x  + zv.y*wa.y  + zv.z*wa.z  + zv.w*wa.w;
                acc[kk][1] += zv.x*wbv.x + zv.y*wbv.y + zv.z*wbv.z + zv.w*wbv.w;
                acc[kk][2] += zv.x*wc.x  + zv.y*wc.y  + zv.z*wc.z  + zv.w*wc.w;
            }
        }
        #pragma unroll
        for (int kk = 0; kk < 4; ++kk)
            #pragma unroll
            for (int j = 0; j < 3; ++j)
                part[cgrp][kgrp + 16*kk][h0 + j] = acc[kk][j];
    }
    __syncthreads();

    // logits: thread = k (t&63), heads h0..h0+2 (t>>6); packed float4 K-side reads
    {
        const int k = t & 63;
        const int h0 = (t >> 6) * 3;
        const int kn = k0 + k;
        const float mterm = (mask[qn]*mask[kn] - 1.f) * 100000.f;
        float biasv[3];
        #pragma unroll
        for (int j = 0; j < 3; ++j)
            biasv[j] = b_b[h0+j] + part[0][k][h0+j] + part[1][k][h0+j]
                     + part[2][k][h0+j] + part[3][k][h0+j];
        #pragma unroll
        for (int j = 0; j < 3; ++j) {
            const int h = h0 + j;
            const float* kkrow = kkP + (size_t)(h*NRES + kn)*16;
            const float* kprow = kptsP + (size_t)(h*NRES + kn)*12;
            const float4 qv0 = *(const float4*)&q_lds[h*16 + 0];
            const float4 qv1 = *(const float4*)&q_lds[h*16 + 4];
            const float4 qv2 = *(const float4*)&q_lds[h*16 + 8];
            const float4 qv3 = *(const float4*)&q_lds[h*16 + 12];
            const float4 k0v = *(const float4*)&kkrow[0];
            const float4 k1v = *(const float4*)&kkrow[4];
            const float4 k2v = *(const float4*)&kkrow[8];
            const float4 k3v = *(const float4*)&kkrow[12];
            float qk = qv0.x*k0v.x + qv0.y*k0v.y + qv0.z*k0v.z + qv0.w*k0v.w
                     + qv1.x*k1v.x + qv1.y*k1v.y + qv1.z*k1v.z + qv1.w*k1v.w
                     + qv2.x*k2v.x + qv2.y*k2v.y + qv2.z*k2v.z + qv2.w*k2v.w
                     + qv3.x*k3v.x + qv3.y*k3v.y + qv3.z*k3v.z + qv3.w*k3v.w;
            const float4 qp0 = *(const float4*)&qp_lds[h*12 + 0];
            const float4 qp1 = *(const float4*)&qp_lds[h*12 + 4];
            const float4 qp2 = *(const float4*)&qp_lds[h*12 + 8];
            const float4 p0 = *(const float4*)&kprow[0];
            const float4 p1 = *(const float4*)&kprow[4];
            const float4 p2 = *(const float4*)&kprow[8];
            float d0 = qp0.x-p0.x, d1 = qp0.y-p0.y, d2 = qp0.z-p0.z, d3 = qp0.w-p0.w;
            float d4 = qp1.x-p1.x, d5 = qp1.y-p1.y, d6 = qp1.z-p1.z, d7 = qp1.w-p1.w;
            float d8 = qp2.x-p2.x, d9 = qp2.y-p2.y, d10 = qp2.z-p2.z, d11 = qp2.w-p2.w;
            float dsum = d0*d0+d1*d1+d2*d2+d3*d3+d4*d4+d5*d5+d6*d6+d7*d7
                       + d8*d8+d9*d9+d10*d10+d11*d11;
            logitsT[(size_t)h*NRES*NRES + (size_t)qn*NRES + kn] =
                0.14433757f*qk + 0.57735027f*biasv[j] - 0.5f*hw_lds[h]*dsum + mterm;
        }
    }
}

// ---------------------------------------------------------------- softmax over logitsT, in-place
// grid 1536 x 256: one wave per (h,q) row of 512.
__global__ __launch_bounds__(256) void k_sm(float* __restrict__ logitsT)
{
    const int lane = threadIdx.x & 63;
    const int r = blockIdx.x * 4 + (threadIdx.x >> 6);   // r = h*512 + q, r < 6144
    float4* row = (float4*)(logitsT + (size_t)r * NRES);

    float4 v0 = row[lane];
    float4 v1 = row[lane + 64];
    float m = fmaxf(fmaxf(fmaxf(v0.x, v0.y), fmaxf(v0.z, v0.w)),
                    fmaxf(fmaxf(v1.x, v1.y), fmaxf(v1.z, v1.w)));
    #pragma unroll
    for (int off = 32; off > 0; off >>= 1) m = fmaxf(m, __shfl_xor(m, off));
    v0.x = __expf(v0.x - m); v0.y = __expf(v0.y - m);
    v0.z = __expf(v0.z - m); v0.w = __expf(v0.w - m);
    v1.x = __expf(v1.x - m); v1.y = __expf(v1.y - m);
    v1.z = __expf(v1.z - m); v1.w = __expf(v1.w - m);
    float ss = v0.x + v0.y + v0.z + v0.w + v1.x + v1.y + v1.z + v1.w;
    #pragma unroll
    for (int off = 32; off > 0; off >>= 1) ss += __shfl_xor(ss, off);
    const float inv = 1.f / ss;
    v0.x *= inv; v0.y *= inv; v0.z *= inv; v0.w *= inv;
    v1.x *= inv; v1.y *= inv; v1.z *= inv; v1.w *= inv;
    row[lane] = v0;
    row[lane + 64] = v1;
}

// ---------------------------------------------------------------- o_pair (z second pass, L3)
__global__ __launch_bounds__(256) void k_pair7(
    const float* __restrict__ z, const float* __restrict__ logitsT,
    float* __restrict__ o_cat)
{
    const int qn = blockIdx.x;
    const int t = threadIdx.x;
    __shared__ float aT[512*20];

    for (int i = t; i < 12*NRES; i += 256) {
        const int h = i >> 9, kn = i & 511;
        aT[kn*20 + h] = logitsT[(size_t)h*NRES*NRES + (size_t)qn*NRES + kn];
    }
    __syncthreads();

    const int lane = t & 63, w = t >> 6;
    const int c4 = w*8 + (lane & 7);
    const int kg = lane >> 3;
    const float4* zp = (const float4*)(z + (size_t)qn*NRES*CZD) + c4;
    float4 acc4[12];
    #pragma unroll
    for (int h = 0; h < 12; ++h) acc4[h] = make_float4(0.f,0.f,0.f,0.f);

    #pragma unroll 4
    for (int i = 0; i < 64; ++i) {
        const int kn = kg + 8*i;
        float4 zv = zp[(size_t)kn*32];
        float4 a0 = *(const float4*)&aT[kn*20 + 0];
        float4 a1 = *(const float4*)&aT[kn*20 + 4];
        float4 a2 = *(const float4*)&aT[kn*20 + 8];
        float av[12] = {a0.x,a0.y,a0.z,a0.w, a1.x,a1.y,a1.z,a1.w, a2.x,a2.y,a2.z,a2.w};
        #pragma unroll
        for (int h = 0; h < 12; ++h) {
            acc4[h].x += av[h]*zv.x; acc4[h].y += av[h]*zv.y;
            acc4[h].z += av[h]*zv.z; acc4[h].w += av[h]*zv.w;
        }
    }
    #pragma unroll
    for (int h = 0; h < 12; ++h) {
        #pragma unroll
        for (int off = 8; off < 64; off <<= 1) {
            acc4[h].x += __shfl_xor(acc4[h].x, off);
            acc4[h].y += __shfl_xor(acc4[h].y, off);
            acc4[h].z += __shfl_xor(acc4[h].z, off);
            acc4[h].w += __shfl_xor(acc4[h].w, off);
        }
    }
    if (kg == 0) {
        float* ob = o_cat + qn*2112 + 576;
        #pragma unroll
        for (int h = 0; h < 12; ++h)
            *(float4*)&ob[h*128 + c4*4] = acc4[h];
    }
}

// ---------------------------------------------------------------- o/o_pt + rotation (no big LDS, high occupancy)
__global__ __launch_bounds__(256) void k_av2(
    const float* __restrict__ logitsT, const float* __restrict__ vcomb,
    const float* __restrict__ rot, const float* __restrict__ trans,
    float* __restrict__ o_cat)
{
    const int qn = blockIdx.x;
    const int t = threadIdx.x;
    __shared__ float optraw[288];

    if (t < 240) {
        const int ch0 = 2*t, ch1 = 2*t + 1;
        const int hA = (ch0 < 192) ? (ch0 >> 4) : (ch0 - 192) / 24;
        const int hB = (ch1 < 192) ? (ch1 >> 4) : (ch1 - 192) / 24;
        const float* rowA = logitsT + ((size_t)hA*NRES + qn)*NRES;
        const float* rowB = logitsT + ((size_t)hB*NRES + qn)*NRES;
        const float2* vp2 = (const float2*)vcomb + t;
        float aAcc = 0.f, bAcc = 0.f;
        #pragma unroll 8
        for (int kn = 0; kn < NRES; ++kn) {
            float2 v = vp2[(size_t)kn*256];
            aAcc += rowA[kn] * v.x;
            bAcc += rowB[kn] * v.y;
        }
        if (ch0 < 192) o_cat[qn*2112 + ch0] = aAcc;
        else           optraw[ch0 - 192] = aAcc;
        if (ch1 < 192) o_cat[qn*2112 + ch1] = bAcc;
        else           optraw[ch1 - 192] = bAcc;
    }
    __syncthreads();

    if (t < 96) {
        const float* R = rot + qn*9;
        const float* T = trans + qn*3;
        float ox = optraw[t*3]   - T[0];
        float oy = optraw[t*3+1] - T[1];
        float oz = optraw[t*3+2] - T[2];
        float x  = R[0]*ox + R[3]*oy + R[6]*oz;
        float y  = R[1]*ox + R[4]*oy + R[7]*oz;
        float zc = R[2]*ox + R[5]*oy + R[8]*oz;
        float* ob = o_cat + qn*2112;
        ob[192 + t] = x;
        ob[288 + t] = y;
        ob[384 + t] = zc;
        ob[480 + t] = sqrtf(x*x + y*y + zc*zc + 1e-8f);
    }
}

// ---------------------------------------------------------------- final GEMM
__global__ __launch_bounds__(256) void k_out2(
    const float* __restrict__ o_cat, const float* __restrict__ w_out, float* __restrict__ part)
{
    const int ct = blockIdx.x;
    const int n0 = blockIdx.y * 32;
    const int kc = blockIdx.z;
    const int t = threadIdx.x;

    __shared__ float oT[32][34];
    __shared__ float wt[32][36];

    const int lr = t >> 3, lc4 = t & 7;
    const int tr = t >> 4, tc = t & 15;
    const int kbase = kc * 352;
    float4 ov4, wv4;

    ov4 = *(const float4*)&o_cat[(n0 + lr) * 2112 + kbase + lc4 * 4];
    wv4 = *(const float4*)&w_out[(kbase + lr) * 384 + ct * 32 + lc4 * 4];
    oT[lc4*4+0][lr] = ov4.x; oT[lc4*4+1][lr] = ov4.y; oT[lc4*4+2][lr] = ov4.z; oT[lc4*4+3][lr] = ov4.w;
    *(float4*)&wt[lr][lc4*4] = wv4;
    __syncthreads();

    float a00 = 0.f, a01 = 0.f, a10 = 0.f, a11 = 0.f;

    for (int it = 0; it < 11; ++it) {
        if (it < 10) {
            const int k0 = kbase + (it + 1) * 32;
            ov4 = *(const float4*)&o_cat[(n0 + lr) * 2112 + k0 + lc4 * 4];
            wv4 = *(const float4*)&w_out[(k0 + lr) * 384 + ct * 32 + lc4 * 4];
        }
        #pragma unroll
        for (int kx = 0; kx < 32; ++kx) {
            float2 oo = *(const float2*)&oT[kx][tr * 2];
            float2 ww = *(const float2*)&wt[kx][tc * 2];
            a00 += oo.x * ww.x; a01 += oo.x * ww.y;
            a10 += oo.y * ww.x; a11 += oo.y * ww.y;
        }
        __syncthreads();
        if (it < 10) {
            oT[lc4*4+0][lr] = ov4.x; oT[lc4*4+1][lr] = ov4.y; oT[lc4*4+2][lr] = ov4.z; oT[lc4*4+3][lr] = ov4.w;
            *(float4*)&wt[lr][lc4*4] = wv4;
            __syncthreads();
        }
    }

    float* pp = part + (size_t)kc * 196608;
    pp[(n0 + tr*2 + 0)*384 + ct*32 + tc*2 + 0] = a00;
    pp[(n0 + tr*2 + 0)*384 + ct*32 + tc*2 + 1] = a01;
    pp[(n0 + tr*2 + 1)*384 + ct*32 + tc*2 + 0] = a10;
    pp[(n0 + tr*2 + 1)*384 + ct*32 + tc*2 + 1] = a11;
}

__global__ __launch_bounds__(256) void k_red(
    const float* __restrict__ part, const float* __restrict__ b_out, float* __restrict__ out)
{
    const int i = blockIdx.x*256 + threadIdx.x;
    float acc = b_out[i % 384];
    #pragma unroll
    for (int dc = 0; dc < 6; ++dc) acc += part[(size_t)dc*196608 + i];
    out[i] = acc;
}

// ----------------------------------------------------------------
extern "C" void kernel_launch(void* const* d_in, const int* in_sizes, int n_in,
                              void* d_out, int out_size, void* d_ws, size_t ws_size,
                              hipStream_t stream) {
    (void)in_sizes; (void)n_in; (void)out_size; (void)ws_size;
    const float* s      = (const float*)d_in[0];
    const float* z      = (const float*)d_in[1];
    const float* rot    = (const float*)d_in[2];
    const float* trans  = (const float*)d_in[3];
    const float* mask   = (const float*)d_in[4];
    const float* w_q    = (const float*)d_in[5];
    const float* b_q    = (const float*)d_in[6];
    const float* w_kv   = (const float*)d_in[7];
    const float* b_kv   = (const float*)d_in[8];
    const float* w_qp   = (const float*)d_in[9];
    const float* b_qp   = (const float*)d_in[10];
    const float* w_kvp  = (const float*)d_in[11];
    const float* b_kvp  = (const float*)d_in[12];
    const float* w_b    = (const float*)d_in[13];
    const float* b_b    = (const float*)d_in[14];
    const float* hwts   = (const float*)d_in[15];
    const float* w_out  = (const float*)d_in[16];
    const float* b_out  = (const float*)d_in[17];
    float* out = (float*)d_out;
    float* ws  = (float*)d_ws;

    float* q       = ws + OFF_Q;
    float* kkP     = ws + OFF_KT;
    float* vcomb   = ws + OFF_VC;
    float* qp      = ws + OFF_QP;
    float* kptsP   = ws + OFF_KPT;
    float* logitsT = ws + OFF_A;
    float* ocat    = ws + OFF_OCAT;
    float* wcat    = ws + OFF_WCAT;
    float* bcat    = ws + OFF_BCAT;
    float* wbT     = ws + OFF_WBT;
    float* part    = ws + OFF_PART;
    float* praw_q  = ws + OFF_PRAWQ;
    float* praw_kv = ws + OFF_PRAWK;

    k_wcat<<<dim3(1739), dim3(256), 0, stream>>>(w_q, b_q, w_kv, b_kv, w_qp, b_qp, w_kvp, b_kvp,
        w_b, wcat, bcat, wbT);
    k_proj2<<<dim3(36, 16), dim3(256), 0, stream>>>(s, wcat, bcat, q, kkP, vcomb, praw_q, praw_kv);
    k_rot<<<dim3(384), dim3(256), 0, stream>>>(praw_q, praw_kv, rot, trans, qp, kptsP, vcomb);
    k_bias4<<<dim3(8, NRES), dim3(256), 0, stream>>>(z, wbT, b_b, q, kkP, qp, kptsP,
        hwts, mask, logitsT);
    k_sm<<<dim3(1536), dim3(256), 0, stream>>>(logitsT);
    k_pair7<<<dim3(NRES), dim3(256), 0, stream>>>(z, logitsT, ocat);
    k_av2<<<dim3(NRES), dim3(256), 0, stream>>>(logitsT, vcomb, rot, trans, ocat);
    k_out2<<<dim3(12, 16, 6), dim3(256), 0, stream>>>(ocat, w_out, part);
    k_red<<<dim3(768), dim3(256), 0, stream>>>(part, b_out, out);
}